// Round 4
// baseline (111.575 us; speedup 1.0000x reference)
//
#include <hip/hip_runtime.h>

// Weighted 2D Procrustes (Kabsch) with z-padding == closed-form 2x2 polar factor.
// B=1024 batches, N=4096 points. Output: R [B,3,3] then t [B,3,1], fp32.
//
// R4: latency-hypothesis test. Stage 1 = 4096 blocks (4 slices/batch, 1024 pts
// each, one load pass of 5x float4 per thread -> max outstanding loads, 16
// blocks/CU). Partial moments (9 fp64) to d_ws. Stage 2 = 1024 blocks combining
// slices in FIXED order (deterministic fp64 — det-sign branch must not flip
// across replays; atomics would be order-nondeterministic) + closed-form solve.

constexpr int BATCH = 1024;
constexpr int NPTS  = 4096;
constexpr int SLICES = 4;                  // points per slice = 1024
constexpr double EPSV = 1e-4;

__device__ __forceinline__ double wredd(double v) {
    #pragma unroll
    for (int off = 1; off < 64; off <<= 1) v += __shfl_xor(v, off, 64);
    return v;
}

__global__ __launch_bounds__(256) void moments_kernel(
    const float* __restrict__ src, const float* __restrict__ tgt,
    const float* __restrict__ wts, double* __restrict__ partial)
{
    const int blk   = blockIdx.x;
    const int b     = blk >> 2;            // batch
    const int slice = blk & 3;
    const int tid   = threadIdx.x;

    const int i = slice * 1024 + tid * 4;  // 4 points per thread, single pass
    const float* sb = src + (size_t)b * (NPTS * 2);
    const float* tb = tgt + (size_t)b * (NPTS * 2);
    const float* wb = wts + (size_t)b * NPTS;

    const float4 wv = *reinterpret_cast<const float4*>(wb + i);
    const float4 sa = *reinterpret_cast<const float4*>(sb + 2 * i);
    const float4 sc = *reinterpret_cast<const float4*>(sb + 2 * i + 4);
    const float4 ta = *reinterpret_cast<const float4*>(tb + 2 * i);
    const float4 tc = *reinterpret_cast<const float4*>(tb + 2 * i + 4);

    const float wf[4]  = {wv.x, wv.y, wv.z, wv.w};
    const float sxf[4] = {sa.x, sa.z, sc.x, sc.z};
    const float syf[4] = {sa.y, sa.w, sc.y, sc.w};
    const float txf[4] = {ta.x, ta.z, tc.x, tc.z};
    const float tyf[4] = {ta.y, ta.w, tc.y, tc.w};

    // acc: 0=sum_w 1=sum w*sx 2=sum w*sy 3=sum w*tx 4=sum w*ty
    //      5=sum w*tx*sx 6=sum w*tx*sy 7=sum w*ty*sx 8=sum w*ty*sy
    double acc[9] = {0,0,0,0,0,0,0,0,0};
    #pragma unroll
    for (int j = 0; j < 4; ++j) {
        const double w  = (double)wf[j];
        const double sx = (double)sxf[j], sy = (double)syf[j];
        const double tx = (double)txf[j], ty = (double)tyf[j];
        acc[0] += w;
        acc[1] = fma(w, sx, acc[1]);
        acc[2] = fma(w, sy, acc[2]);
        acc[3] = fma(w, tx, acc[3]);
        acc[4] = fma(w, ty, acc[4]);
        const double wt0 = w * tx, wt1 = w * ty;
        acc[5] = fma(wt0, sx, acc[5]);
        acc[6] = fma(wt0, sy, acc[6]);
        acc[7] = fma(wt1, sx, acc[7]);
        acc[8] = fma(wt1, sy, acc[8]);
    }

    #pragma unroll
    for (int k = 0; k < 9; ++k) acc[k] = wredd(acc[k]);

    __shared__ double red[4][9];
    const int lane = tid & 63, wave = tid >> 6;
    if (lane == 0) {
        #pragma unroll
        for (int k = 0; k < 9; ++k) red[wave][k] = acc[k];
    }
    __syncthreads();

    if (tid < 9) {
        const int k = tid;
        partial[(size_t)blk * 9 + k] =
            red[0][k] + red[1][k] + red[2][k] + red[3][k];
    }
}

__global__ __launch_bounds__(64) void solve_kernel(
    const double* __restrict__ partial, float* __restrict__ out)
{
    const int b    = blockIdx.x;
    const int lane = threadIdx.x;

    __shared__ double s[9];
    if (lane < 9) {
        double v = 0.0;
        #pragma unroll
        for (int j = 0; j < SLICES; ++j)        // fixed order: deterministic
            v += partial[((size_t)b * SLICES + j) * 9 + lane];
        s[lane] = v;
    }
    __syncthreads();

    if (lane == 0) {
        const double w   = s[0] + EPSV;
        const double inv = 1.0 / w;
        const double scx = s[1] * inv, scy = s[2] * inv;   // src centroid (z=0)
        const double tcx = s[3] * inv, tcy = s[4] * inv;   // tgt centroid (z=0)

        // A_ij = sum w*t_i*s_j - (sum w*t_i)(sum w*s_j)/w  (scale-invariant)
        const double a00 = s[5] - s[3] * s[1] * inv;
        const double a01 = s[6] - s[3] * s[2] * inv;
        const double a10 = s[7] - s[4] * s[1] * inv;
        const double a11 = s[8] - s[4] * s[2] * inv;

        const double p = 0.5 * (a00 + a11);   // rotation part:   p*I + q*J
        const double q = 0.5 * (a10 - a01);
        const double r = 0.5 * (a00 - a11);   // reflection part: r*K + t*L
        const double t = 0.5 * (a01 + a10);

        const double rot2 = p * p + q * q;
        const double ref2 = r * r + t * t;    // det A = rot2 - ref2

        double R00, R01, R10, R11, Rzz;
        if (rot2 >= ref2) {                   // det(A) >= 0: closest rotation
            const double n = rsqrt(fmax(rot2, 1e-300));
            R00 =  p * n; R01 = -q * n;
            R10 =  q * n; R11 =  p * n;
            Rzz = 1.0;
        } else {                              // det(A) < 0: closest reflection
            const double n = rsqrt(fmax(ref2, 1e-300));
            R00 =  r * n; R01 =  t * n;
            R10 =  t * n; R11 = -r * n;
            Rzz = -1.0;
        }

        // t1 = src_c - R^T tgt_c ; t2 = -R t1   (z components exactly 0)
        const double t1x = scx - (R00 * tcx + R10 * tcy);
        const double t1y = scy - (R01 * tcx + R11 * tcy);
        const double t2x = -(R00 * t1x + R01 * t1y);
        const double t2y = -(R10 * t1x + R11 * t1y);

        float* Ro = out + (size_t)b * 9;
        Ro[0] = (float)R00; Ro[1] = (float)R01; Ro[2] = 0.0f;
        Ro[3] = (float)R10; Ro[4] = (float)R11; Ro[5] = 0.0f;
        Ro[6] = 0.0f;       Ro[7] = 0.0f;       Ro[8] = (float)Rzz;

        float* To = out + (size_t)BATCH * 9 + (size_t)b * 3;
        To[0] = (float)t2x; To[1] = (float)t2y; To[2] = 0.0f;
    }
}

extern "C" void kernel_launch(void* const* d_in, const int* in_sizes, int n_in,
                              void* d_out, int out_size, void* d_ws, size_t ws_size,
                              hipStream_t stream) {
    const float* src = (const float*)d_in[0];
    const float* tgt = (const float*)d_in[1];
    const float* wts = (const float*)d_in[2];
    float* out = (float*)d_out;
    double* partial = (double*)d_ws;       // 4096 * 9 * 8 B = 288 KiB

    moments_kernel<<<BATCH * SLICES, 256, 0, stream>>>(src, tgt, wts, partial);
    solve_kernel<<<BATCH, 64, 0, stream>>>(partial, out);
}

// Round 5
// 102.605 us; speedup vs baseline: 1.0874x; 1.0874x over previous
//
#include <hip/hip_runtime.h>

// Weighted 2D Procrustes (Kabsch) with z-padding == closed-form 2x2 polar factor.
// B=1024 batches, N=4096 points. Output: R [B,3,3] then t [B,3,1], fp32.
//
// R5 = R3 (measured best, 102.8 us) with explicit load hoisting: all 20
// float4 loads (320 B/thread) issue before any arithmetic -> max memory-level
// parallelism guaranteed at source level. Single kernel (R4 proved a second
// dispatch costs ~8 us, far more than any latency win).
//
// Moments + det-sign decision in fp64: det(A) ties within fp32 accumulation
// noise occur for ~1/1024 random batches and flipped the Rzz branch across
// graph replays in R1. Fixed-order fp64 summation is replay-invariant.

constexpr int BATCH = 1024;
constexpr int NPTS  = 4096;
constexpr double EPSV = 1e-4;

__device__ __forceinline__ double wredd(double v) {
    #pragma unroll
    for (int off = 1; off < 64; off <<= 1) v += __shfl_xor(v, off, 64);
    return v;
}

__global__ __launch_bounds__(256) void procrustes_kernel(
    const float* __restrict__ src, const float* __restrict__ tgt,
    const float* __restrict__ wts, float* __restrict__ out)
{
    const int b   = blockIdx.x;
    const int tid = threadIdx.x;
    const float* sb = src + (size_t)b * (NPTS * 2);
    const float* tb = tgt + (size_t)b * (NPTS * 2);
    const float* wb = wts + (size_t)b * NPTS;

    // ---- issue ALL loads first (20 x float4 = 320 B/thread, coalesced) ----
    float4 wv[4], s0[4], s1[4], t0[4], t1[4];
    #pragma unroll
    for (int pass = 0; pass < 4; ++pass) {
        const int i = tid * 4 + pass * 1024;
        wv[pass] = *reinterpret_cast<const float4*>(wb + i);
        s0[pass] = *reinterpret_cast<const float4*>(sb + 2 * i);
        s1[pass] = *reinterpret_cast<const float4*>(sb + 2 * i + 4);
        t0[pass] = *reinterpret_cast<const float4*>(tb + 2 * i);
        t1[pass] = *reinterpret_cast<const float4*>(tb + 2 * i + 4);
    }

    // acc: 0=sum_w 1=sum w*sx 2=sum w*sy 3=sum w*tx 4=sum w*ty
    //      5=sum w*tx*sx 6=sum w*tx*sy 7=sum w*ty*sx 8=sum w*ty*sy
    double acc[9] = {0,0,0,0,0,0,0,0,0};

    #pragma unroll
    for (int pass = 0; pass < 4; ++pass) {
        const float wf[4]  = {wv[pass].x, wv[pass].y, wv[pass].z, wv[pass].w};
        const float sxf[4] = {s0[pass].x, s0[pass].z, s1[pass].x, s1[pass].z};
        const float syf[4] = {s0[pass].y, s0[pass].w, s1[pass].y, s1[pass].w};
        const float txf[4] = {t0[pass].x, t0[pass].z, t1[pass].x, t1[pass].z};
        const float tyf[4] = {t0[pass].y, t0[pass].w, t1[pass].y, t1[pass].w};

        #pragma unroll
        for (int j = 0; j < 4; ++j) {
            const double w  = (double)wf[j];
            const double sx = (double)sxf[j], sy = (double)syf[j];
            const double tx = (double)txf[j], ty = (double)tyf[j];
            acc[0] += w;
            acc[1] = fma(w, sx, acc[1]);
            acc[2] = fma(w, sy, acc[2]);
            acc[3] = fma(w, tx, acc[3]);
            acc[4] = fma(w, ty, acc[4]);
            const double wt0 = w * tx, wt1 = w * ty;
            acc[5] = fma(wt0, sx, acc[5]);
            acc[6] = fma(wt0, sy, acc[6]);
            acc[7] = fma(wt1, sx, acc[7]);
            acc[8] = fma(wt1, sy, acc[8]);
        }
    }

    // wave64 butterfly reduce, then cross-wave via LDS (4 waves).
    #pragma unroll
    for (int k = 0; k < 9; ++k) acc[k] = wredd(acc[k]);

    __shared__ double red[4][9];
    const int lane = tid & 63, wave = tid >> 6;
    if (lane == 0) {
        #pragma unroll
        for (int k = 0; k < 9; ++k) red[wave][k] = acc[k];
    }
    __syncthreads();

    if (tid == 0) {
        double s[9];
        #pragma unroll
        for (int k = 0; k < 9; ++k)
            s[k] = red[0][k] + red[1][k] + red[2][k] + red[3][k];

        const double w   = s[0] + EPSV;
        const double inv = 1.0 / w;
        const double scx = s[1] * inv, scy = s[2] * inv;   // src centroid (z=0)
        const double tcx = s[3] * inv, tcy = s[4] * inv;   // tgt centroid (z=0)

        // A_ij = sum w*t_i*s_j - (sum w*t_i)(sum w*s_j)/w  (scale-invariant)
        const double a00 = s[5] - s[3] * s[1] * inv;
        const double a01 = s[6] - s[3] * s[2] * inv;
        const double a10 = s[7] - s[4] * s[1] * inv;
        const double a11 = s[8] - s[4] * s[2] * inv;

        const double p = 0.5 * (a00 + a11);   // rotation part:   p*I + q*J
        const double q = 0.5 * (a10 - a01);
        const double r = 0.5 * (a00 - a11);   // reflection part: r*K + t*L
        const double t = 0.5 * (a01 + a10);

        const double rot2 = p * p + q * q;
        const double ref2 = r * r + t * t;    // det A = rot2 - ref2

        double R00, R01, R10, R11, Rzz;
        if (rot2 >= ref2) {                   // det(A) >= 0: closest rotation
            const double n = rsqrt(fmax(rot2, 1e-300));
            R00 =  p * n; R01 = -q * n;
            R10 =  q * n; R11 =  p * n;
            Rzz = 1.0;
        } else {                              // det(A) < 0: closest reflection
            const double n = rsqrt(fmax(ref2, 1e-300));
            R00 =  r * n; R01 =  t * n;
            R10 =  t * n; R11 = -r * n;
            Rzz = -1.0;
        }

        // t1 = src_c - R^T tgt_c ; t2 = -R t1   (z components exactly 0)
        const double t1x = scx - (R00 * tcx + R10 * tcy);
        const double t1y = scy - (R01 * tcx + R11 * tcy);
        const double t2x = -(R00 * t1x + R01 * t1y);
        const double t2y = -(R10 * t1x + R11 * t1y);

        float* Ro = out + (size_t)b * 9;
        Ro[0] = (float)R00; Ro[1] = (float)R01; Ro[2] = 0.0f;
        Ro[3] = (float)R10; Ro[4] = (float)R11; Ro[5] = 0.0f;
        Ro[6] = 0.0f;       Ro[7] = 0.0f;       Ro[8] = (float)Rzz;

        float* To = out + (size_t)BATCH * 9 + (size_t)b * 3;
        To[0] = (float)t2x; To[1] = (float)t2y; To[2] = 0.0f;
    }
}

extern "C" void kernel_launch(void* const* d_in, const int* in_sizes, int n_in,
                              void* d_out, int out_size, void* d_ws, size_t ws_size,
                              hipStream_t stream) {
    const float* src = (const float*)d_in[0];
    const float* tgt = (const float*)d_in[1];
    const float* wts = (const float*)d_in[2];
    float* out = (float*)d_out;
    procrustes_kernel<<<BATCH, 256, 0, stream>>>(src, tgt, wts, out);
}